// Round 14
// baseline (334.155 us; speedup 1.0000x reference)
//
#include <hip/hip_runtime.h>
#include <stdint.h>
#include <stddef.h>

typedef int v4i __attribute__((ext_vector_type(4)));

#define GLOAD_LDS16(g, l) __builtin_amdgcn_global_load_lds( \
    (const __attribute__((address_space(1))) void*)(g),     \
    (__attribute__((address_space(3))) void*)(l), 16, 0, 0)

// ---------------------------------------------------------------------------
// Quantize rows of length 2048: one wave per row, 4 rows per 256-thread block.
// scale = max(amax/127, floorv); q = clip(rint(v/scale), -128, 127)
// ---------------------------------------------------------------------------
__device__ __forceinline__ int pack4(float4 f, float s) {
    int a = (int)rintf(f.x / s); a = a < -128 ? -128 : (a > 127 ? 127 : a);
    int b = (int)rintf(f.y / s); b = b < -128 ? -128 : (b > 127 ? 127 : b);
    int c = (int)rintf(f.z / s); c = c < -128 ? -128 : (c > 127 ? 127 : c);
    int d = (int)rintf(f.w / s); d = d < -128 ? -128 : (d > 127 ? 127 : d);
    return (a & 255) | ((b & 255) << 8) | ((c & 255) << 16) | ((d & 255) << 24);
}

__global__ __launch_bounds__(256) void quant_rows_2048(
    const float* __restrict__ in, signed char* __restrict__ q,
    float* __restrict__ scales, float floorv)
{
    const int lane = threadIdx.x & 63;
    const int row  = blockIdx.x * 4 + (threadIdx.x >> 6);
    const float* rp = in + (size_t)row * 2048;

    float4 v[8];
#pragma unroll
    for (int j = 0; j < 2; ++j) {
        const float4* p = (const float4*)(rp + j * 1024 + lane * 16);
#pragma unroll
        for (int i = 0; i < 4; ++i) v[j * 4 + i] = p[i];
    }
    float am = 0.0f;
#pragma unroll
    for (int i = 0; i < 8; ++i) {
        am = fmaxf(am, fabsf(v[i].x));
        am = fmaxf(am, fabsf(v[i].y));
        am = fmaxf(am, fabsf(v[i].z));
        am = fmaxf(am, fabsf(v[i].w));
    }
#pragma unroll
    for (int off = 32; off; off >>= 1) am = fmaxf(am, __shfl_xor(am, off));
    const float s = fmaxf(am / 127.0f, floorv);

#pragma unroll
    for (int j = 0; j < 2; ++j) {
        int4 pk;
        pk.x = pack4(v[j * 4 + 0], s);
        pk.y = pack4(v[j * 4 + 1], s);
        pk.z = pack4(v[j * 4 + 2], s);
        pk.w = pack4(v[j * 4 + 3], s);
        *(int4*)(q + (size_t)row * 2048 + j * 1024 + lane * 16) = pk;
    }
    if (lane == 0) scales[row] = s;
}

// ---------------------------------------------------------------------------
// int8 GEMM — R9 skeleton (best: loose single-barrier ring-3, 2 blocks/CU)
// + REGISTER DOUBLE-BUFFER at tile granularity: ds_reads of tile t+1's
// fragments are issued DURING tile t's window and consumed next window, so
// ds latency + lgkm drain hide under the MFMA cluster's pipe drain.
// 128x256 tile, BK=64, 512 thr = 8 waves (2M x 4N), wave 64x64 via 4x4 frags
// of mfma_i32_16x16x64_i8. LDS ring-3 x 24KB = 72 KB -> 2 blocks/CU.
// Window t: {ST3(t+2); 8 ds_read frags(t+1) -> nf; sched_barrier;
//   setprio(1) 16 MFMA on cf setprio(0); vmcnt(0)+lgkm(0); s_barrier; cf<-nf}.
// vmcnt(0) here is free: every load drained has >= 1 full window (~3000 cyc)
// of slack (issued at window top, waited at window bottom / next window).
// WAR-safe under <=1-barrier drift: ahead-wave in t+1 stages buf t%3; a
// lagging wave in t reads only buf (t+1)%3 and registers.
// Swizzle: LDS slot s of row r holds global chunk s ^ ((r>>1)&3) (2-way=free).
// ---------------------------------------------------------------------------
__global__ __launch_bounds__(512, 4) void gemm_i8_rdb(
    const signed char* __restrict__ xq, const signed char* __restrict__ wq,
    const float* __restrict__ xs, const float* __restrict__ ws,
    const float* __restrict__ bias, float* __restrict__ out, int K)
{
    __shared__ __align__(16) signed char lds[73728]; // 3 x (A 8K | B 16K)

    const int tid  = threadIdx.x;
    const int lane = tid & 63;
    const int wid  = tid >> 6;
    const int wm   = wid >> 2;        // 0..1
    const int wn   = wid & 3;         // 0..3

    const int nwg  = gridDim.x * gridDim.y;
    int orig = blockIdx.y * gridDim.x + blockIdx.x;
    int swz  = ((nwg & 7) == 0) ? ((orig & 7) * (nwg >> 3) + (orig >> 3)) : orig;
    const int brow = (swz / gridDim.x) * 128;
    const int bcol = (swz % gridDim.x) * 256;

    // staging: thread -> (row = tid>>2 in 0..127, chunk = tid&3), swizzled src
    const int gch  = (((tid & 3) ^ ((tid >> 3) & 3)) << 4);
    const int lofs = tid << 4;
    const signed char* gA  = xq + (size_t)(brow + (tid >> 2)) * K;
    const signed char* gB0 = wq + (size_t)(bcol + (tid >> 2)) * K;
    const signed char* gB1 = wq + (size_t)(bcol + 128 + (tid >> 2)) * K;

#define BUFOFF(bb) ((bb) * 24576)
#define ST3(tt, bb) do {                                                         \
    GLOAD_LDS16(gA  + (size_t)(tt) * 64 + gch, lds + BUFOFF(bb) + lofs);         \
    GLOAD_LDS16(gB0 + (size_t)(tt) * 64 + gch, lds + BUFOFF(bb) + 8192 + lofs);  \
    GLOAD_LDS16(gB1 + (size_t)(tt) * 64 + gch, lds + BUFOFF(bb) + 16384 + lofs); \
} while (0)

    const int rl   = lane & 15;
    const int ko   = lane >> 4;
    const int slot = ((ko ^ ((rl >> 1) & 3)) << 4);

#define FRAG_A(bb, r) (*(const v4i*)(lds + BUFOFF(bb) + (r) * 64 + slot))
#define FRAG_B(bb, r) (*(const v4i*)(lds + BUFOFF(bb) + 8192 + (r) * 64 + slot))

    v4i acc[4][4] = {};
    const int ar = wm * 64 + rl;
    const int br = wn * 64 + rl;

    // ---- prologue: stage tiles 0,1; wait tile 0 (counted), barrier
    ST3(0, 0);
    ST3(1, 1);
    asm volatile("s_waitcnt vmcnt(3)" ::: "memory");
    __builtin_amdgcn_s_barrier();

    // preload frags(0) into current regs (compiler inserts lgkm wait at use)
    v4i ca0 = FRAG_A(0, ar);
    v4i ca1 = FRAG_A(0, ar + 16);
    v4i ca2 = FRAG_A(0, ar + 32);
    v4i ca3 = FRAG_A(0, ar + 48);
    v4i cb0 = FRAG_B(0, br);
    v4i cb1 = FRAG_B(0, br + 16);
    v4i cb2 = FRAG_B(0, br + 32);
    v4i cb3 = FRAG_B(0, br + 48);

    const int NT = K >> 6;   // 32
    for (int t = 0; t < NT; ++t) {
        if (t + 2 < NT) ST3(t + 2, (t + 2) % 3);

        v4i na0, na1, na2, na3, nb0, nb1, nb2, nb3;
        if (t + 1 < NT) {
            const int nb = (t + 1) % 3;
            na0 = FRAG_A(nb, ar);
            na1 = FRAG_A(nb, ar + 16);
            na2 = FRAG_A(nb, ar + 32);
            na3 = FRAG_A(nb, ar + 48);
            nb0 = FRAG_B(nb, br);
            nb1 = FRAG_B(nb, br + 16);
            nb2 = FRAG_B(nb, br + 32);
            nb3 = FRAG_B(nb, br + 48);
        }
        __builtin_amdgcn_sched_barrier(0);   // keep reads above the MFMA cluster

        __builtin_amdgcn_s_setprio(1);
#pragma unroll
        for (int m = 0; m < 4; ++m) {
            v4i a = (m == 0) ? ca0 : (m == 1) ? ca1 : (m == 2) ? ca2 : ca3;
            acc[m][0] = __builtin_amdgcn_mfma_i32_16x16x64_i8(a, cb0, acc[m][0], 0, 0, 0);
            acc[m][1] = __builtin_amdgcn_mfma_i32_16x16x64_i8(a, cb1, acc[m][1], 0, 0, 0);
            acc[m][2] = __builtin_amdgcn_mfma_i32_16x16x64_i8(a, cb2, acc[m][2], 0, 0, 0);
            acc[m][3] = __builtin_amdgcn_mfma_i32_16x16x64_i8(a, cb3, acc[m][3], 0, 0, 0);
        }
        __builtin_amdgcn_s_setprio(0);

        if (t + 1 < NT) {
            // all loads waited here were issued >= one full window earlier
            asm volatile("s_waitcnt vmcnt(0) lgkmcnt(0)" ::: "memory");
            __builtin_amdgcn_s_barrier();
            ca0 = na0; ca1 = na1; ca2 = na2; ca3 = na3;
            cb0 = nb0; cb1 = nb1; cb2 = nb2; cb3 = nb3;
        }
    }

    // ---- epilogue: C/D layout col = lane&15, row = (lane>>4)*4 + j
    const int rg = lane >> 4;
#pragma unroll
    for (int n = 0; n < 4; ++n) {
        const int col = bcol + wn * 64 + n * 16 + rl;
        const float wsc = ws[col];
        const float bv  = bias[col];
#pragma unroll
        for (int m = 0; m < 4; ++m) {
#pragma unroll
            for (int j = 0; j < 4; ++j) {
                const int row = brow + wm * 64 + m * 16 + rg * 4 + j;
                out[(size_t)row * 2048 + col] =
                    (float)acc[m][n][j] * xs[row] * wsc + bv;
            }
        }
    }
#undef ST3
#undef BUFOFF
#undef FRAG_A
#undef FRAG_B
}

// ---------------------------------------------------------------------------
extern "C" void kernel_launch(void* const* d_in, const int* in_sizes, int n_in,
                              void* d_out, int out_size, void* d_ws, size_t ws_size,
                              hipStream_t stream) {
    const float* x    = (const float*)d_in[0];   // [B,N,D] = [4,4096,2048]
    const float* w    = (const float*)d_in[1];   // [O,D]   = [2048,2048]
    const float* bias = (const float*)d_in[2];   // [O]
    float* out = (float*)d_out;

    const int D = 2048;
    const int O = in_sizes[2];                   // 2048
    const int M = in_sizes[0] / D;               // 16384

    char* wsb = (char*)d_ws;
    signed char* xq  = (signed char*)wsb;
    signed char* wqp = (signed char*)(wsb + (size_t)M * D);
    float* xs  = (float*)(wsb + (size_t)M * D + (size_t)O * D);
    float* wsc = (float*)(wsb + (size_t)M * D + (size_t)O * D + (size_t)M * 4);

    quant_rows_2048<<<M / 4, 256, 0, stream>>>(x, xq, xs, 1e-12f);
    quant_rows_2048<<<O / 4, 256, 0, stream>>>(w, wqp, wsc, 1e-8f / 127.0f);

    dim3 grid(O / 256, M / 128);   // (8, 128) = 1024 blocks, %8 == 0
    gemm_i8_rdb<<<grid, 512, 0, stream>>>(xq, wqp, xs, wsc, bias, out, D);
}

// Round 15
// 126.343 us; speedup vs baseline: 2.6448x; 2.6448x over previous
//
#include <hip/hip_runtime.h>
#include <stdint.h>
#include <stddef.h>

typedef int v4i __attribute__((ext_vector_type(4)));

#define GLOAD_LDS16(g, l) __builtin_amdgcn_global_load_lds( \
    (const __attribute__((address_space(1))) void*)(g),     \
    (__attribute__((address_space(3))) void*)(l), 16, 0, 0)

// ---------------------------------------------------------------------------
// Quantize rows of length 2048: one wave per row, 4 rows per 256-thread block.
// scale = max(amax/127, floorv); q = clip(rint(v/scale), -128, 127)
// ---------------------------------------------------------------------------
__device__ __forceinline__ int pack4(float4 f, float s) {
    int a = (int)rintf(f.x / s); a = a < -128 ? -128 : (a > 127 ? 127 : a);
    int b = (int)rintf(f.y / s); b = b < -128 ? -128 : (b > 127 ? 127 : b);
    int c = (int)rintf(f.z / s); c = c < -128 ? -128 : (c > 127 ? 127 : c);
    int d = (int)rintf(f.w / s); d = d < -128 ? -128 : (d > 127 ? 127 : d);
    return (a & 255) | ((b & 255) << 8) | ((c & 255) << 16) | ((d & 255) << 24);
}

__global__ __launch_bounds__(256) void quant_rows_2048(
    const float* __restrict__ in, signed char* __restrict__ q,
    float* __restrict__ scales, float floorv)
{
    const int lane = threadIdx.x & 63;
    const int row  = blockIdx.x * 4 + (threadIdx.x >> 6);
    const float* rp = in + (size_t)row * 2048;

    float4 v[8];
#pragma unroll
    for (int j = 0; j < 2; ++j) {
        const float4* p = (const float4*)(rp + j * 1024 + lane * 16);
#pragma unroll
        for (int i = 0; i < 4; ++i) v[j * 4 + i] = p[i];
    }
    float am = 0.0f;
#pragma unroll
    for (int i = 0; i < 8; ++i) {
        am = fmaxf(am, fabsf(v[i].x));
        am = fmaxf(am, fabsf(v[i].y));
        am = fmaxf(am, fabsf(v[i].z));
        am = fmaxf(am, fabsf(v[i].w));
    }
#pragma unroll
    for (int off = 32; off; off >>= 1) am = fmaxf(am, __shfl_xor(am, off));
    const float s = fmaxf(am / 127.0f, floorv);

#pragma unroll
    for (int j = 0; j < 2; ++j) {
        int4 pk;
        pk.x = pack4(v[j * 4 + 0], s);
        pk.y = pack4(v[j * 4 + 1], s);
        pk.z = pack4(v[j * 4 + 2], s);
        pk.w = pack4(v[j * 4 + 3], s);
        *(int4*)(q + (size_t)row * 2048 + j * 1024 + lane * 16) = pk;
    }
    if (lane == 0) scales[row] = s;
}

// ---------------------------------------------------------------------------
// int8 GEMM — R9 structure (best of 14 rounds: loose single-barrier ring-3,
// 2 blocks/CU) with two m190-backed micro-edits:
//  (1) NO setprio around MFMA (m190: setprio hurts barrier-lockstep GEMM).
//  (2) ds_reads issued BEFORE the ST3 gloads (reads are on this window's
//      critical path; stages have 2 windows of slack).
// 128x256 tile, BK=64, 512 thr = 8 waves (2M x 4N), wave 64x64 via 4x4 frags
// of mfma_i32_16x16x64_i8. LDS ring-3 x 24KB = 72 KB -> 2 blocks/CU.
// Per tile t: {8 ds_read frags of t%3; ST3(t+2)->(t+2)%3; 16 MFMA (compiler
//   lgkm waits); lgkmcnt(0)+vmcnt(3) counted; raw s_barrier}.
// vmcnt never 0 mid-loop; the 3 ops left in flight are ST3(t+2) (2-window
// slack). lgkmcnt(0) pre-barrier kills the ring WAR race.
// Swizzle: LDS slot s of row r holds global chunk s ^ ((r>>1)&3) (2-way=free).
// ---------------------------------------------------------------------------
__global__ __launch_bounds__(512, 4) void gemm_i8_ring(
    const signed char* __restrict__ xq, const signed char* __restrict__ wq,
    const float* __restrict__ xs, const float* __restrict__ ws,
    const float* __restrict__ bias, float* __restrict__ out, int K)
{
    __shared__ __align__(16) signed char lds[73728]; // 3 x (A 8K | B 16K)

    const int tid  = threadIdx.x;
    const int lane = tid & 63;
    const int wid  = tid >> 6;
    const int wm   = wid >> 2;        // 0..1
    const int wn   = wid & 3;         // 0..3

    const int nwg  = gridDim.x * gridDim.y;
    int orig = blockIdx.y * gridDim.x + blockIdx.x;
    int swz  = ((nwg & 7) == 0) ? ((orig & 7) * (nwg >> 3) + (orig >> 3)) : orig;
    const int brow = (swz / gridDim.x) * 128;
    const int bcol = (swz % gridDim.x) * 256;

    // staging: thread -> (row = tid>>2 in 0..127, chunk = tid&3), swizzled src
    const int gch  = (((tid & 3) ^ ((tid >> 3) & 3)) << 4);
    const int lofs = tid << 4;
    const signed char* gA  = xq + (size_t)(brow + (tid >> 2)) * K;
    const signed char* gB0 = wq + (size_t)(bcol + (tid >> 2)) * K;
    const signed char* gB1 = wq + (size_t)(bcol + 128 + (tid >> 2)) * K;

#define BUFOFF(bb) ((bb) * 24576)
#define ST3(tt, bb) do {                                                         \
    GLOAD_LDS16(gA  + (size_t)(tt) * 64 + gch, lds + BUFOFF(bb) + lofs);         \
    GLOAD_LDS16(gB0 + (size_t)(tt) * 64 + gch, lds + BUFOFF(bb) + 8192 + lofs);  \
    GLOAD_LDS16(gB1 + (size_t)(tt) * 64 + gch, lds + BUFOFF(bb) + 16384 + lofs); \
} while (0)

    const int rl   = lane & 15;
    const int ko   = lane >> 4;
    const int slot = ((ko ^ ((rl >> 1) & 3)) << 4);

#define FRAG_A(bb, r) (*(const v4i*)(lds + BUFOFF(bb) + (r) * 64 + slot))
#define FRAG_B(bb, r) (*(const v4i*)(lds + BUFOFF(bb) + 8192 + (r) * 64 + slot))

    v4i acc[4][4] = {};
    const int ar = wm * 64 + rl;
    const int br = wn * 64 + rl;

    // ---- prologue: stage tiles 0,1; wait tile 0 (counted), barrier
    ST3(0, 0);
    ST3(1, 1);
    asm volatile("s_waitcnt vmcnt(3)" ::: "memory");
    __builtin_amdgcn_s_barrier();

    const int NT = K >> 6;   // 32
    for (int t = 0; t < NT; ++t) {
        const int buf = t % 3;

        // reads first (critical path), then next-next stage (2-window slack)
        v4i af[4], bf[4];
#pragma unroll
        for (int m = 0; m < 4; ++m) af[m] = FRAG_A(buf, ar + m * 16);
#pragma unroll
        for (int n = 0; n < 4; ++n) bf[n] = FRAG_B(buf, br + n * 16);

        if (t + 2 < NT) ST3(t + 2, (t + 2) % 3);

#pragma unroll
        for (int m = 0; m < 4; ++m)
#pragma unroll
            for (int n = 0; n < 4; ++n)
                acc[m][n] = __builtin_amdgcn_mfma_i32_16x16x64_i8(
                    af[m], bf[n], acc[m][n], 0, 0, 0);

        if (t + 2 < NT) {
            // t+1 resident (its 3 loads drained), t+2's 3 stay in flight
            asm volatile("s_waitcnt vmcnt(3) lgkmcnt(0)" ::: "memory");
            __builtin_amdgcn_s_barrier();
        } else if (t + 2 == NT) {
            asm volatile("s_waitcnt vmcnt(0) lgkmcnt(0)" ::: "memory");
            __builtin_amdgcn_s_barrier();
        }
        // t == NT-1: no further loads, fall through to epilogue
    }

    // ---- epilogue: C/D layout col = lane&15, row = (lane>>4)*4 + j
    const int rg = lane >> 4;
#pragma unroll
    for (int n = 0; n < 4; ++n) {
        const int col = bcol + wn * 64 + n * 16 + rl;
        const float wsc = ws[col];
        const float bv  = bias[col];
#pragma unroll
        for (int m = 0; m < 4; ++m) {
#pragma unroll
            for (int j = 0; j < 4; ++j) {
                const int row = brow + wm * 64 + m * 16 + rg * 4 + j;
                out[(size_t)row * 2048 + col] =
                    (float)acc[m][n][j] * xs[row] * wsc + bv;
            }
        }
    }
#undef ST3
#undef BUFOFF
#undef FRAG_A
#undef FRAG_B
}

// ---------------------------------------------------------------------------
extern "C" void kernel_launch(void* const* d_in, const int* in_sizes, int n_in,
                              void* d_out, int out_size, void* d_ws, size_t ws_size,
                              hipStream_t stream) {
    const float* x    = (const float*)d_in[0];   // [B,N,D] = [4,4096,2048]
    const float* w    = (const float*)d_in[1];   // [O,D]   = [2048,2048]
    const float* bias = (const float*)d_in[2];   // [O]
    float* out = (float*)d_out;

    const int D = 2048;
    const int O = in_sizes[2];                   // 2048
    const int M = in_sizes[0] / D;               // 16384

    char* wsb = (char*)d_ws;
    signed char* xq  = (signed char*)wsb;
    signed char* wqp = (signed char*)(wsb + (size_t)M * D);
    float* xs  = (float*)(wsb + (size_t)M * D + (size_t)O * D);
    float* wsc = (float*)(wsb + (size_t)M * D + (size_t)O * D + (size_t)M * 4);

    quant_rows_2048<<<M / 4, 256, 0, stream>>>(x, xq, xs, 1e-12f);
    quant_rows_2048<<<O / 4, 256, 0, stream>>>(w, wqp, wsc, 1e-8f / 127.0f);

    dim3 grid(O / 256, M / 128);   // (8, 128) = 1024 blocks, %8 == 0
    gemm_i8_ring<<<grid, 512, 0, stream>>>(xq, wqp, xs, wsc, bias, out, D);
}